// Round 13
// baseline (86.497 us; speedup 1.0000x reference)
//
#include <hip/hip_runtime.h>
#include <stdint.h>

#define RH 224
#define RW 224
#define NSTRIPE 3                      // row-stripes per image (75/75/74 rows)
#define NCHUNK 32                      // point-chunks per batch
#define MAXROWS 75                     // max rows per stripe
#define MAXPX (MAXROWS * RW)           // 16800 slots -> 67200 B dynamic LDS
#define BLOCK_THREADS 1024
#define QPT 4                          // quads per thread
#define NPT (QPT * 4)                  // points per thread (16) -> pix[16] regs

// FP policy (FROZEN — bit-exact vs ref=np since round 8, absmax 0.0):
// numpy f32 einsum scalar tail: FORWARD accumulation, separate mul/add
// rounds, no FMA; all later elementwise ops separately rounded.
// `#pragma clang fp contract(off)` everywhere FP happens.
//
// Perf history:
//  r8  389us: 8M scattered device atomics (atomic-op bound, VALU 3.5%)
//  r9  739us: guard-load REGRESSED (8M dependent HBM guard reads)
//  r10  81us: LDS stripe z-buffer NSTRIPE=4, 1 blk/CU (VALU 65%)
//  r11  57us: NSTRIPE=2, FETCH compulsory, VALU 47% @ occ 38%
//  r12  68us: NSTRIPE=3 2blk/CU REGRESSED — VALU-cycles scale exactly with
//             visits (1.51x); occupancy buys back only ~2/3. Lesson:
//             reduce PROJECTIONS per point, not add waves.
//  r13: project ONCE into reg-cached pixel index (pix[16], static unroll),
//       then 3 cheap stripe scans (compare + LDS atomicMax). launch_bounds
//       (1024,8) caps VGPR at 64 -> 2 blocks/CU co-resident (32 waves).

#pragma clang fp contract(off)

__device__ __forceinline__ float dot3_fwd_nofma(float v0, float v1, float v2,
                                                float R0, float R1, float R2,
                                                float t) {
#pragma clang fp contract(off)
    const float p0 = v0 * R0;
    const float p1 = v1 * R1;
    const float p2 = v2 * R2;
    float acc = p0 + p1;
    acc = acc + p2;
    acc = acc + t;
    return acc;
}

// Pass 1: blocks = (batch b, chunk c). Pass A: project chunk points once,
// cache pixel index in registers. Pass B (x3 stripes): scan cache, LDS
// atomicMax, coalesced global flush.
__global__ __launch_bounds__(BLOCK_THREADS, 8) void
proj_kernel(const float* __restrict__ vertices,
            const float* __restrict__ rotation,
            const float* __restrict__ translation,
            const float* __restrict__ Kmat,
            unsigned int* __restrict__ win,  // = d_out as u32
            int N) {
#pragma clang fp contract(off)
    extern __shared__ unsigned int sbuf[];   // MAXPX u32 = 67200 B

    const int blk = (int)blockIdx.x;
    const int c   = blk % NCHUNK;
    const int b   = blk / NCHUNK;

    // Per-batch params (block-uniform -> scalar regs).
    const float* R = rotation + b * 9;
    const float* t = translation + b * 3;
    const float* k = Kmat + b * 9;
    const float fx = k[0], cx = k[2], fy = k[4], cy = k[5];
    const float R00 = R[0], R01 = R[1], R02 = R[2];
    const float R10 = R[3], R11 = R[4], R12 = R[5];
    const float R20 = R[6], R21 = R[7], R22 = R[8];
    const float t0 = t[0], t1 = t[1], t2 = t[2];

    // Chunk bounds; chunk size padded to a multiple of 4 for float4 loads.
    const int chunk = (((N + NCHUNK - 1) / NCHUNK) + 3) & ~3;
    const int n_beg = c * chunk;
    const int n_end = min(N, n_beg + chunk);
    const int tid   = (int)threadIdx.x;

    // ---- Pass A: project each point ONCE; cache pixel idx (or ~0u). ----
    unsigned int pix[NPT];
#pragma unroll
    for (int qi = 0; qi < QPT; ++qi) {
        const int n0 = n_beg + ((qi * BLOCK_THREADS + tid) << 2);
        // Defaults: invalid.
        pix[qi * 4 + 0] = 0xFFFFFFFFu;
        pix[qi * 4 + 1] = 0xFFFFFFFFu;
        pix[qi * 4 + 2] = 0xFFFFFFFFu;
        pix[qi * 4 + 3] = 0xFFFFFFFFu;
        if (n0 >= n_end) continue;
        // 4 points = 48B = 3x float4 (n0 multiple of 4 -> 16B aligned).
        const float4* vp = (const float4*)(vertices + ((size_t)b * N + n0) * 3);
        const float4 f0 = vp[0], f1 = vp[1], f2 = vp[2];
        const float pv[4][3] = {{f0.x, f0.y, f0.z}, {f0.w, f1.x, f1.y},
                                {f1.z, f1.w, f2.x}, {f2.y, f2.z, f2.w}};
#pragma unroll
        for (int kk = 0; kk < 4; ++kk) {
            const int n = n0 + kk;
            if (n >= n_end) break;
            const float v0 = pv[kk][0], v1 = pv[kk][1], v2 = pv[kk][2];

            // FROZEN FP ORDER (separate rounds, forward accumulation).
            const float y = dot3_fwd_nofma(v0, v1, v2, R10, R11, R12, t1);
            const float z = dot3_fwd_nofma(v0, v1, v2, R20, R21, R22, t2);
            const float Z = z + 1e-8f;          // separate round
            const float qy = y / Z;             // correctly-rounded div
            float w = fy * qy;                  // separate mul
            w = w + cy;                         // separate add
            const float tv = truncf(w);
            if (!(tv >= 0.0f && tv < (float)RH)) continue;  // NaN -> skip

            const float x = dot3_fwd_nofma(v0, v1, v2, R00, R01, R02, t0);
            const float qx = x / Z;
            float u = fx * qx;
            u = u + cx;
            const float tu = truncf(u);
            if (!(tu >= 0.0f && tu < (float)RW)) continue;

            pix[qi * 4 + kk] = (unsigned int)((int)tv * RW + (int)tu);
        }
    }

    // ---- Pass B: per stripe, scan cached indices -> LDS -> flush. ----
    for (int s = 0; s < NSTRIPE; ++s) {
        const int row_lo = s * MAXROWS;
        const int row_hi = min(RH, row_lo + MAXROWS);
        const unsigned int p_lo = (unsigned int)(row_lo * RW);
        const unsigned int p_hi = (unsigned int)(row_hi * RW);
        const int px = (int)(p_hi - p_lo);

        for (int j = tid; j < px; j += BLOCK_THREADS) sbuf[j] = 0u;
        __syncthreads();

#pragma unroll
        for (int i = 0; i < NPT; ++i) {
            const unsigned int p = pix[i];
            if (p >= p_lo && p < p_hi) {        // ~0u always fails
                const int n = n_beg + (((i >> 2) * BLOCK_THREADS + tid) << 2) + (i & 3);
                const unsigned int order1 = (unsigned int)(b * N + n) + 1u;
                atomicMax(&sbuf[p - p_lo], order1);
            }
        }
        __syncthreads();

        unsigned int* g = win + b * (RH * RW) + p_lo;
        for (int j = tid; j < px; j += BLOCK_THREADS) {
            const unsigned int val = sbuf[j];
            if (val) atomicMax(&g[j], val);
        }
        __syncthreads();   // protect sbuf re-zeroing next stripe
    }
}

// Pass 2: in-place decode winner order -> depth (identical FP sequence).
__global__ void resolve_kernel(unsigned int* __restrict__ buf,  // = d_out
                               const float* __restrict__ vertices,
                               const float* __restrict__ rotation,
                               const float* __restrict__ translation,
                               int N, int P) {
#pragma clang fp contract(off)
    const int i = blockIdx.x * blockDim.x + threadIdx.x;
    if (i >= P) return;
    const unsigned int o1 = buf[i];
    float depth = 0.0f;
    if (o1 != 0u) {
        const unsigned int o = o1 - 1u;
        const int b = (int)(o / (unsigned int)N);
        const int n = (int)(o % (unsigned int)N);
        const float* v = vertices + ((size_t)b * (size_t)N + (size_t)n) * 3;
        const float* R = rotation + b * 9;
        depth = dot3_fwd_nofma(v[0], v[1], v[2], R[6], R[7], R[8],
                               translation[b * 3 + 2]);
    }
    buf[i] = __float_as_uint(depth);  // final f32 image, written as bits
}

extern "C" void kernel_launch(void* const* d_in, const int* in_sizes, int n_in,
                              void* d_out, int out_size, void* d_ws, size_t ws_size,
                              hipStream_t stream) {
    const float* vertices    = (const float*)d_in[0];
    const float* rotation    = (const float*)d_in[1];
    const float* translation = (const float*)d_in[2];
    const float* Kmat        = (const float*)d_in[3];

    const int B = in_sizes[1] / 9;              // rotation is B*3*3
    const int N = in_sizes[0] / (3 * B);        // vertices is B*N*3
    const int P = B * RH * RW;                  // == out_size

    unsigned int* win = (unsigned int*)d_out;

    // d_out must start at 0 every call (harness poisons once, never restores).
    hipMemsetAsync(win, 0, (size_t)P * sizeof(unsigned int), stream);

    dim3 grid(B * NCHUNK);                      // 512 blocks = 2/CU resident
    proj_kernel<<<grid, BLOCK_THREADS, MAXPX * sizeof(unsigned int), stream>>>(
        vertices, rotation, translation, Kmat, win, N);

    const int rblocks = (P + 255) / 256;
    resolve_kernel<<<rblocks, 256, 0, stream>>>(win, vertices, rotation,
                                                translation, N, P);
}

// Round 14
// 60.026 us; speedup vs baseline: 1.4410x; 1.4410x over previous
//
#include <hip/hip_runtime.h>
#include <stdint.h>

#define RH 224
#define RW 224
#define NSTRIPE 2                      // row-stripes per image
#define NCHUNK 8                       // point-chunks per batch
#define STRIPE_ROWS (RH / NSTRIPE)     // 112
#define STRIPE_PX (STRIPE_ROWS * RW)   // 25088 -> 100352 B LDS (u32, dynamic)
#define BLOCK_THREADS 1024

// FP policy (FROZEN — bit-exact vs ref=np since round 8, absmax 0.0):
// numpy f32 einsum scalar tail: FORWARD accumulation, separate mul/add
// rounds, no FMA; all later elementwise ops separately rounded.
// `#pragma clang fp contract(off)` everywhere FP happens.
//
// Perf history:
//  r8  389us: 8M scattered device atomics (atomic-op bound, VALU 3.5%)
//  r9  739us: guard-load REGRESSED (8M dependent HBM guard reads)
//  r10  81us: LDS stripe z-buffer NSTRIPE=4 (VALU 65%)
//  r11  57us: NSTRIPE=2 — best. Model: VALU 27us + flush-atomic TAIL 19us
//             (1 blk/CU -> no overlap) + HBM 15us.
//  r12  68us: NSTRIPE=3 REGRESSED (visit cost dominates occupancy gain)
//  r13  78us: project-once REGRESSED (flush line-RMWs 400K->1.6M; flush
//             traffic = grid x stripe-lines — small chunks kill aggregation)
//  r14: r11 geometry, but flush -> PLAIN uint4 stores into per-block d_ws
//       slices (25.7MB streaming); resolve does 8-way max. Zero global
//       atomics. Fallback to r11 atomic path if ws_size too small.

#pragma clang fp contract(off)

__device__ __forceinline__ float dot3_fwd_nofma(float v0, float v1, float v2,
                                                float R0, float R1, float R2,
                                                float t) {
#pragma clang fp contract(off)
    const float p0 = v0 * R0;
    const float p1 = v1 * R1;
    const float p2 = v2 * R2;
    float acc = p0 + p1;
    acc = acc + p2;
    acc = acc + t;
    return acc;
}

// Shared projection + LDS z-buffer body. FLUSH_WS: store stripe to private ws
// slice (plain stores) vs atomicMax into win (fallback).
template <bool FLUSH_WS>
__global__ __launch_bounds__(BLOCK_THREADS) void
proj_kernel(const float* __restrict__ vertices,
            const float* __restrict__ rotation,
            const float* __restrict__ translation,
            const float* __restrict__ Kmat,
            unsigned int* __restrict__ win,   // d_out as u32 (fallback path)
            unsigned int* __restrict__ ws,    // staged stripes (ws path)
            int N) {
#pragma clang fp contract(off)
    extern __shared__ unsigned int sbuf[];   // STRIPE_PX u32 = 100352 B

    const int blk = (int)blockIdx.x;
    const int s   = blk & (NSTRIPE - 1);             // stripe fastest
    const int c   = (blk >> 1) & (NCHUNK - 1);       // then chunk
    const int b   = blk >> 4;                        // then batch

    for (int j = threadIdx.x; j < STRIPE_PX; j += BLOCK_THREADS) sbuf[j] = 0u;
    __syncthreads();

    // Per-batch params (block-uniform -> scalar regs).
    const float* R = rotation + b * 9;
    const float* t = translation + b * 3;
    const float* k = Kmat + b * 9;
    const float fx = k[0], cx = k[2], fy = k[4], cy = k[5];
    const float R00 = R[0], R01 = R[1], R02 = R[2];
    const float R10 = R[3], R11 = R[4], R12 = R[5];
    const float R20 = R[6], R21 = R[7], R22 = R[8];
    const float t0 = t[0], t1 = t[1], t2 = t[2];

    const int chunk  = (N + NCHUNK - 1) / NCHUNK;    // 62500 (mult of 4)
    const int n_beg  = c * chunk;
    const int n_end  = min(N, n_beg + chunk);
    const int nquads = (n_end - n_beg + 3) >> 2;
    const float v_lo = (float)(s * STRIPE_ROWS);
    const float v_hi = (float)((s + 1) * STRIPE_ROWS);

    for (int q = threadIdx.x; q < nquads; q += BLOCK_THREADS) {
        const int n0 = n_beg + (q << 2);
        // 4 points = 48B = 3x float4 (n0 multiple of 4 -> 16B aligned).
        const float4* vp = (const float4*)(vertices + ((size_t)b * N + n0) * 3);
        const float4 f0 = vp[0], f1 = vp[1], f2 = vp[2];
        const float pxv[4][3] = {{f0.x, f0.y, f0.z}, {f0.w, f1.x, f1.y},
                                 {f1.z, f1.w, f2.x}, {f2.y, f2.z, f2.w}};
#pragma unroll
        for (int kk = 0; kk < 4; ++kk) {
            const int n = n0 + kk;
            if (n >= n_end) break;
            const float v0 = pxv[kk][0], v1 = pxv[kk][1], v2 = pxv[kk][2];

            // FROZEN FP ORDER. v-row first: off-stripe points skip x/u math.
            const float y = dot3_fwd_nofma(v0, v1, v2, R10, R11, R12, t1);
            const float z = dot3_fwd_nofma(v0, v1, v2, R20, R21, R22, t2);
            const float Z = z + 1e-8f;          // separate round
            const float qy = y / Z;             // correctly-rounded div
            float w = fy * qy;                  // separate mul
            w = w + cy;                         // separate add
            const float tv = truncf(w);
            if (!(tv >= v_lo && tv < v_hi)) continue;   // NaN -> skip (== ref)

            const float x = dot3_fwd_nofma(v0, v1, v2, R00, R01, R02, t0);
            const float qx = x / Z;
            float u = fx * qx;
            u = u + cx;
            const float tu = truncf(u);
            if (!(tu >= 0.0f && tu < (float)RW)) continue;

            const int ui = (int)tu;
            const int vi = (int)tv;
            const int slot = (vi - s * STRIPE_ROWS) * RW + ui;
            const unsigned int order1 = (unsigned int)(b * N + n) + 1u;
            atomicMax(&sbuf[slot], order1);     // LDS atomic: cheap
        }
    }
    __syncthreads();

    if (FLUSH_WS) {
        // Plain uint4 streaming stores into this block's private ws slice.
        uint4* dst = (uint4*)(ws + (size_t)blk * STRIPE_PX);
        const uint4* src = (const uint4*)sbuf;
        for (int j = threadIdx.x; j < STRIPE_PX / 4; j += BLOCK_THREADS)
            dst[j] = src[j];
    } else {
        unsigned int* g = win + b * (RH * RW) + s * STRIPE_PX;
        for (int j = threadIdx.x; j < STRIPE_PX; j += BLOCK_THREADS) {
            const unsigned int val = sbuf[j];
            if (val) atomicMax(&g[j], val);
        }
    }
}

// Resolve (ws path): per pixel, max over the NCHUNK chunk-copies, decode
// winner order -> recompute depth with the identical FP sequence.
__global__ void resolve_ws_kernel(const unsigned int* __restrict__ ws,
                                  const float* __restrict__ vertices,
                                  const float* __restrict__ rotation,
                                  const float* __restrict__ translation,
                                  float* __restrict__ out, int N, int P) {
#pragma clang fp contract(off)
    const int i = blockIdx.x * blockDim.x + threadIdx.x;
    if (i >= P) return;
    const int b    = i / (RH * RW);
    const int rc   = i - b * (RH * RW);
    const int row  = rc / RW;
    const int s    = row / STRIPE_ROWS;
    const int slot = (row - s * STRIPE_ROWS) * RW + (rc - row * RW);

    // Base of the 8 chunk-copies for (b, s): blk = (b*8 + c)*2 + s.
    const unsigned int* base = ws + ((size_t)((b * NCHUNK) * NSTRIPE + s)) * STRIPE_PX + slot;
    unsigned int m = 0u;
#pragma unroll
    for (int c = 0; c < NCHUNK; ++c) {
        const unsigned int val = base[(size_t)c * NSTRIPE * STRIPE_PX];
        m = max(m, val);
    }

    float depth = 0.0f;
    if (m != 0u) {
        const unsigned int o = m - 1u;
        const int bb = (int)(o / (unsigned int)N);
        const int n  = (int)(o % (unsigned int)N);
        const float* v = vertices + ((size_t)bb * (size_t)N + (size_t)n) * 3;
        const float* R = rotation + bb * 9;
        depth = dot3_fwd_nofma(v[0], v[1], v[2], R[6], R[7], R[8],
                               translation[bb * 3 + 2]);
    }
    out[i] = depth;
}

// Resolve (fallback path): in-place decode of the atomic win buffer.
__global__ void resolve_kernel(unsigned int* __restrict__ buf,  // = d_out
                               const float* __restrict__ vertices,
                               const float* __restrict__ rotation,
                               const float* __restrict__ translation,
                               int N, int P) {
#pragma clang fp contract(off)
    const int i = blockIdx.x * blockDim.x + threadIdx.x;
    if (i >= P) return;
    const unsigned int o1 = buf[i];
    float depth = 0.0f;
    if (o1 != 0u) {
        const unsigned int o = o1 - 1u;
        const int b = (int)(o / (unsigned int)N);
        const int n = (int)(o % (unsigned int)N);
        const float* v = vertices + ((size_t)b * (size_t)N + (size_t)n) * 3;
        const float* R = rotation + b * 9;
        depth = dot3_fwd_nofma(v[0], v[1], v[2], R[6], R[7], R[8],
                               translation[b * 3 + 2]);
    }
    buf[i] = __float_as_uint(depth);
}

extern "C" void kernel_launch(void* const* d_in, const int* in_sizes, int n_in,
                              void* d_out, int out_size, void* d_ws, size_t ws_size,
                              hipStream_t stream) {
    const float* vertices    = (const float*)d_in[0];
    const float* rotation    = (const float*)d_in[1];
    const float* translation = (const float*)d_in[2];
    const float* Kmat        = (const float*)d_in[3];

    const int B = in_sizes[1] / 9;              // rotation is B*3*3
    const int N = in_sizes[0] / (3 * B);        // vertices is B*N*3
    const int P = B * RH * RW;                  // == out_size
    const int nblocks = B * NSTRIPE * NCHUNK;   // 256 = 1 block/CU

    const size_t ws_needed = (size_t)nblocks * STRIPE_PX * sizeof(unsigned int);

    if (ws_size >= ws_needed) {
        // Fast path: staged flush, no global atomics, no memset.
        unsigned int* ws = (unsigned int*)d_ws;
        proj_kernel<true><<<nblocks, BLOCK_THREADS,
                            STRIPE_PX * sizeof(unsigned int), stream>>>(
            vertices, rotation, translation, Kmat, nullptr, ws, N);
        const int rblocks = (P + 255) / 256;
        resolve_ws_kernel<<<rblocks, 256, 0, stream>>>(
            ws, vertices, rotation, translation, (float*)d_out, N, P);
    } else {
        // Fallback: r11 atomic-flush path.
        unsigned int* win = (unsigned int*)d_out;
        hipMemsetAsync(win, 0, (size_t)P * sizeof(unsigned int), stream);
        proj_kernel<false><<<nblocks, BLOCK_THREADS,
                             STRIPE_PX * sizeof(unsigned int), stream>>>(
            vertices, rotation, translation, Kmat, win, nullptr, N);
        const int rblocks = (P + 255) / 256;
        resolve_kernel<<<rblocks, 256, 0, stream>>>(win, vertices, rotation,
                                                    translation, N, P);
    }
}

// Round 15
// 48.034 us; speedup vs baseline: 1.8008x; 1.2497x over previous
//
#include <hip/hip_runtime.h>
#include <stdint.h>

#define RH 224
#define RW 224
#define HW (RH * RW)                   // 50176 pixels
#define NCHUNK 16                      // chunks per batch; local order < 2^16
#define BLOCK_THREADS 1024
#define LDSW (HW / 2)                  // 25088 u32 words = 100352 B (u16/px)

// FP policy (FROZEN — bit-exact vs ref=np since round 8, absmax 0.0):
// numpy f32 einsum scalar tail: FORWARD accumulation, separate mul/add
// rounds, no FMA; all later elementwise ops separately rounded.
// `#pragma clang fp contract(off)` everywhere FP happens.
//
// Perf history:
//  r8  389us: scattered device atomics | r9 739us guard-load REGRESS
//  r10  81us: LDS stripes x4 | r11 57us: stripes x2 (VALU 27us + flush
//  tail 19us + HBM 15us) | r12 68us stripes x3 REGRESS | r13 78us
//  project-once+atomic-flush REGRESS (flush line-RMWs) | r14 60us:
//  ws-staged plain-store flush (no global atomics).
//  r15: FULL image in LDS as u16 (chunk-local order fits 16 bits since
//  chunk=31252<2^16; cross-chunk priority is free: higher chunk always
//  wins). Each point projected ONCE. u16 max via u32 CAS loop (~1.25
//  hits/px/block -> first-try success). Flush/resolve as r14 with 16
//  copies and key=(c+1)<<16|local.

#pragma clang fp contract(off)

__device__ __forceinline__ float dot3_fwd_nofma(float v0, float v1, float v2,
                                                float R0, float R1, float R2,
                                                float t) {
#pragma clang fp contract(off)
    const float p0 = v0 * R0;
    const float p1 = v1 * R1;
    const float p2 = v2 * R2;
    float acc = p0 + p1;
    acc = acc + p2;
    acc = acc + t;
    return acc;
}

// ---------------- fast path: project once, u16 LDS z-buffer ----------------
__global__ __launch_bounds__(BLOCK_THREADS) void
proj16_kernel(const float* __restrict__ vertices,
              const float* __restrict__ rotation,
              const float* __restrict__ translation,
              const float* __restrict__ Kmat,
              unsigned int* __restrict__ ws,   // staged u16 images (as u32)
              int N, int chunk) {
#pragma clang fp contract(off)
    extern __shared__ unsigned int sbuf[];     // LDSW u32 = HW u16

    const int blk = (int)blockIdx.x;           // blk = b*NCHUNK + c
    const int c   = blk % NCHUNK;
    const int b   = blk / NCHUNK;

    for (int j = threadIdx.x; j < LDSW; j += BLOCK_THREADS) sbuf[j] = 0u;
    __syncthreads();

    // Per-batch params (block-uniform -> scalar regs).
    const float* R = rotation + b * 9;
    const float* t = translation + b * 3;
    const float* k = Kmat + b * 9;
    const float fx = k[0], cx = k[2], fy = k[4], cy = k[5];
    const float R00 = R[0], R01 = R[1], R02 = R[2];
    const float R10 = R[3], R11 = R[4], R12 = R[5];
    const float R20 = R[6], R21 = R[7], R22 = R[8];
    const float t0 = t[0], t1 = t[1], t2 = t[2];

    const int n_beg  = c * chunk;              // chunk % 4 == 0 -> aligned
    const int n_end  = min(N, n_beg + chunk);
    const int nquads = (n_end - n_beg + 3) >> 2;

    for (int q = threadIdx.x; q < nquads; q += BLOCK_THREADS) {
        const int n0 = n_beg + (q << 2);
        // 4 points = 48B = 3x float4 (n0 multiple of 4 -> 16B aligned).
        const float4* vp = (const float4*)(vertices + ((size_t)b * N + n0) * 3);
        const float4 f0 = vp[0], f1 = vp[1], f2 = vp[2];
        const float pxv[4][3] = {{f0.x, f0.y, f0.z}, {f0.w, f1.x, f1.y},
                                 {f1.z, f1.w, f2.x}, {f2.y, f2.z, f2.w}};
#pragma unroll
        for (int kk = 0; kk < 4; ++kk) {
            const int n = n0 + kk;
            if (n >= n_end) break;
            const float v0 = pxv[kk][0], v1 = pxv[kk][1], v2 = pxv[kk][2];

            // FROZEN FP ORDER (single exact projection per point).
            const float y = dot3_fwd_nofma(v0, v1, v2, R10, R11, R12, t1);
            const float z = dot3_fwd_nofma(v0, v1, v2, R20, R21, R22, t2);
            const float Z = z + 1e-8f;          // separate round
            const float qy = y / Z;             // correctly-rounded div
            float w = fy * qy;                  // separate mul
            w = w + cy;                         // separate add
            const float tv = truncf(w);
            if (!(tv >= 0.0f && tv < (float)RH)) continue;  // NaN -> skip

            const float x = dot3_fwd_nofma(v0, v1, v2, R00, R01, R02, t0);
            const float qx = x / Z;
            float u = fx * qx;
            u = u + cx;
            const float tu = truncf(u);
            if (!(tu >= 0.0f && tu < (float)RW)) continue;

            const unsigned int p  = (unsigned int)((int)tv * RW + (int)tu);
            const unsigned int sh = (p & 1u) << 4;        // halfword shift
            const unsigned int val = (unsigned int)(n - n_beg + 1);  // <=chunk
            unsigned int* wp = &sbuf[p >> 1];
            unsigned int cur = *wp;
            while (((cur >> sh) & 0xFFFFu) < val) {       // u16 CAS-max
                const unsigned int nw =
                    (cur & ~(0xFFFFu << sh)) | (val << sh);
                const unsigned int prev = atomicCAS(wp, cur, nw);
                if (prev == cur) break;
                cur = prev;
            }
        }
    }
    __syncthreads();

    // Plain uint4 streaming stores into this block's private ws slice.
    uint4* dst = (uint4*)(ws + (size_t)blk * LDSW);
    const uint4* src = (const uint4*)sbuf;
    for (int j = threadIdx.x; j < LDSW / 4; j += BLOCK_THREADS)
        dst[j] = src[j];
}

// Resolve: per pixel, key-max over the NCHUNK u16 copies (higher chunk always
// wins); decode n = c*chunk + local - 1; recompute depth (frozen FP).
__global__ void resolve16_kernel(const unsigned short* __restrict__ ws16,
                                 const float* __restrict__ vertices,
                                 const float* __restrict__ rotation,
                                 const float* __restrict__ translation,
                                 float* __restrict__ out, int N, int chunk,
                                 int P) {
#pragma clang fp contract(off)
    const int i = blockIdx.x * blockDim.x + threadIdx.x;
    if (i >= P) return;
    const int b   = i / HW;
    const int pix = i - b * HW;

    const unsigned short* base = ws16 + ((size_t)b * NCHUNK) * HW + pix;
    unsigned int m = 0u;
#pragma unroll
    for (int c = 0; c < NCHUNK; ++c) {
        const unsigned int v = (unsigned int)base[(size_t)c * HW];
        const unsigned int key = v ? (((unsigned int)(c + 1) << 16) | v) : 0u;
        m = max(m, key);
    }

    float depth = 0.0f;
    if (m != 0u) {
        const int c = (int)(m >> 16) - 1;
        const int n = c * chunk + (int)(m & 0xFFFFu) - 1;
        const float* v = vertices + ((size_t)b * (size_t)N + (size_t)n) * 3;
        const float* R = rotation + b * 9;
        depth = dot3_fwd_nofma(v[0], v[1], v[2], R[6], R[7], R[8],
                               translation[b * 3 + 2]);
    }
    out[i] = depth;
}

// ---------------- fallback path (r11: u32 LDS stripes + atomic flush) ------
#define NSTRIPE 2
#define STRIPE_ROWS (RH / NSTRIPE)
#define STRIPE_PX (STRIPE_ROWS * RW)

__global__ __launch_bounds__(BLOCK_THREADS) void
proj_fb_kernel(const float* __restrict__ vertices,
               const float* __restrict__ rotation,
               const float* __restrict__ translation,
               const float* __restrict__ Kmat,
               unsigned int* __restrict__ win, int N) {
#pragma clang fp contract(off)
    extern __shared__ unsigned int sbuf[];
    const int blk = (int)blockIdx.x;
    const int s   = blk & (NSTRIPE - 1);
    const int c   = (blk >> 1) & 7;
    const int b   = blk >> 4;
    for (int j = threadIdx.x; j < STRIPE_PX; j += BLOCK_THREADS) sbuf[j] = 0u;
    __syncthreads();
    const float* R = rotation + b * 9;
    const float* t = translation + b * 3;
    const float* k = Kmat + b * 9;
    const float fx = k[0], cx = k[2], fy = k[4], cy = k[5];
    const float R00 = R[0], R01 = R[1], R02 = R[2];
    const float R10 = R[3], R11 = R[4], R12 = R[5];
    const float R20 = R[6], R21 = R[7], R22 = R[8];
    const float t0 = t[0], t1 = t[1], t2 = t[2];
    const int chunk  = (N + 7) / 8;
    const int n_beg  = c * chunk;
    const int n_end  = min(N, n_beg + chunk);
    const int nquads = (n_end - n_beg + 3) >> 2;
    const float v_lo = (float)(s * STRIPE_ROWS);
    const float v_hi = (float)((s + 1) * STRIPE_ROWS);
    for (int q = threadIdx.x; q < nquads; q += BLOCK_THREADS) {
        const int n0 = n_beg + (q << 2);
        const float4* vp = (const float4*)(vertices + ((size_t)b * N + n0) * 3);
        const float4 f0 = vp[0], f1 = vp[1], f2 = vp[2];
        const float pxv[4][3] = {{f0.x, f0.y, f0.z}, {f0.w, f1.x, f1.y},
                                 {f1.z, f1.w, f2.x}, {f2.y, f2.z, f2.w}};
#pragma unroll
        for (int kk = 0; kk < 4; ++kk) {
            const int n = n0 + kk;
            if (n >= n_end) break;
            const float v0 = pxv[kk][0], v1 = pxv[kk][1], v2 = pxv[kk][2];
            const float y = dot3_fwd_nofma(v0, v1, v2, R10, R11, R12, t1);
            const float z = dot3_fwd_nofma(v0, v1, v2, R20, R21, R22, t2);
            const float Z = z + 1e-8f;
            const float qy = y / Z;
            float w = fy * qy;
            w = w + cy;
            const float tv = truncf(w);
            if (!(tv >= v_lo && tv < v_hi)) continue;
            const float x = dot3_fwd_nofma(v0, v1, v2, R00, R01, R02, t0);
            const float qx = x / Z;
            float u = fx * qx;
            u = u + cx;
            const float tu = truncf(u);
            if (!(tu >= 0.0f && tu < (float)RW)) continue;
            const int slot = ((int)tv - s * STRIPE_ROWS) * RW + (int)tu;
            atomicMax(&sbuf[slot], (unsigned int)(b * N + n) + 1u);
        }
    }
    __syncthreads();
    unsigned int* g = win + b * HW + s * STRIPE_PX;
    for (int j = threadIdx.x; j < STRIPE_PX; j += BLOCK_THREADS) {
        const unsigned int val = sbuf[j];
        if (val) atomicMax(&g[j], val);
    }
}

__global__ void resolve_fb_kernel(unsigned int* __restrict__ buf,
                                  const float* __restrict__ vertices,
                                  const float* __restrict__ rotation,
                                  const float* __restrict__ translation,
                                  int N, int P) {
#pragma clang fp contract(off)
    const int i = blockIdx.x * blockDim.x + threadIdx.x;
    if (i >= P) return;
    const unsigned int o1 = buf[i];
    float depth = 0.0f;
    if (o1 != 0u) {
        const unsigned int o = o1 - 1u;
        const int b = (int)(o / (unsigned int)N);
        const int n = (int)(o % (unsigned int)N);
        const float* v = vertices + ((size_t)b * (size_t)N + (size_t)n) * 3;
        const float* R = rotation + b * 9;
        depth = dot3_fwd_nofma(v[0], v[1], v[2], R[6], R[7], R[8],
                               translation[b * 3 + 2]);
    }
    buf[i] = __float_as_uint(depth);
}

extern "C" void kernel_launch(void* const* d_in, const int* in_sizes, int n_in,
                              void* d_out, int out_size, void* d_ws, size_t ws_size,
                              hipStream_t stream) {
    const float* vertices    = (const float*)d_in[0];
    const float* rotation    = (const float*)d_in[1];
    const float* translation = (const float*)d_in[2];
    const float* Kmat        = (const float*)d_in[3];

    const int B = in_sizes[1] / 9;              // rotation is B*3*3
    const int N = in_sizes[0] / (3 * B);        // vertices is B*N*3
    const int P = B * HW;                       // == out_size
    const int nblocks = B * NCHUNK;             // 256 = 1 block/CU
    const int chunk = (((N + NCHUNK - 1) / NCHUNK) + 3) & ~3;  // 31252, %4==0

    const size_t ws_needed = (size_t)nblocks * LDSW * sizeof(unsigned int);

    if (ws_size >= ws_needed && chunk < 65536) {
        unsigned int* ws = (unsigned int*)d_ws;
        proj16_kernel<<<nblocks, BLOCK_THREADS,
                        LDSW * sizeof(unsigned int), stream>>>(
            vertices, rotation, translation, Kmat, ws, N, chunk);
        const int rblocks = (P + 255) / 256;
        resolve16_kernel<<<rblocks, 256, 0, stream>>>(
            (const unsigned short*)d_ws, vertices, rotation, translation,
            (float*)d_out, N, chunk, P);
    } else {
        unsigned int* win = (unsigned int*)d_out;
        hipMemsetAsync(win, 0, (size_t)P * sizeof(unsigned int), stream);
        proj_fb_kernel<<<B * 16, BLOCK_THREADS,
                         STRIPE_PX * sizeof(unsigned int), stream>>>(
            vertices, rotation, translation, Kmat, win, N);
        const int rblocks = (P + 255) / 256;
        resolve_fb_kernel<<<rblocks, 256, 0, stream>>>(win, vertices, rotation,
                                                       translation, N, P);
    }
}

// Round 16
// 47.415 us; speedup vs baseline: 1.8243x; 1.0131x over previous
//
#include <hip/hip_runtime.h>
#include <stdint.h>

#define RH 224
#define RW 224
#define HW (RH * RW)                   // 50176 pixels
#define NCHUNK 16                      // chunks per batch; local order < 2^16
#define BLOCK_THREADS 1024
#define LDSW (HW / 2)                  // 25088 u32 words = 100352 B (u16/px)

// FP policy (FROZEN — bit-exact vs ref=np since round 8, absmax 0.0):
// numpy f32 einsum scalar tail: FORWARD accumulation, separate mul/add
// rounds, no FMA; all later elementwise ops separately rounded.
// `#pragma clang fp contract(off)` everywhere FP happens.
//
// Perf history:
//  r8 389us scattered global atomics | r9 739us guard-load REGRESS
//  r10 81us LDS stripes x4 | r11 57us stripes x2 | r12 68us stripes x3
//  REGRESS | r13 78us project-once+atomic-flush REGRESS | r14 60us
//  ws-staged plain-store flush | r15 48us full-image u16 LDS + CAS-max,
//  project ONCE (proj ~35us, resolve ~12us).
//  r16: resolve vectorized 4px/thread (uint2 loads, cndmask overwrite —
//  ascending-chunk scan makes key-max a conditional move); proj uint4 init.

#pragma clang fp contract(off)

__device__ __forceinline__ float dot3_fwd_nofma(float v0, float v1, float v2,
                                                float R0, float R1, float R2,
                                                float t) {
#pragma clang fp contract(off)
    const float p0 = v0 * R0;
    const float p1 = v1 * R1;
    const float p2 = v2 * R2;
    float acc = p0 + p1;
    acc = acc + p2;
    acc = acc + t;
    return acc;
}

// ---------------- fast path: project once, u16 LDS z-buffer ----------------
__global__ __launch_bounds__(BLOCK_THREADS) void
proj16_kernel(const float* __restrict__ vertices,
              const float* __restrict__ rotation,
              const float* __restrict__ translation,
              const float* __restrict__ Kmat,
              unsigned int* __restrict__ ws,   // staged u16 images (as u32)
              int N, int chunk) {
#pragma clang fp contract(off)
    extern __shared__ unsigned int sbuf[];     // LDSW u32 = HW u16

    const int blk = (int)blockIdx.x;           // blk = b*NCHUNK + c
    const int c   = blk % NCHUNK;
    const int b   = blk / NCHUNK;

    // uint4 zero-init (6272 vector stores / block).
    {
        uint4* s4 = (uint4*)sbuf;
        const uint4 z = {0u, 0u, 0u, 0u};
        for (int j = threadIdx.x; j < LDSW / 4; j += BLOCK_THREADS) s4[j] = z;
    }
    __syncthreads();

    // Per-batch params (block-uniform -> scalar regs).
    const float* R = rotation + b * 9;
    const float* t = translation + b * 3;
    const float* k = Kmat + b * 9;
    const float fx = k[0], cx = k[2], fy = k[4], cy = k[5];
    const float R00 = R[0], R01 = R[1], R02 = R[2];
    const float R10 = R[3], R11 = R[4], R12 = R[5];
    const float R20 = R[6], R21 = R[7], R22 = R[8];
    const float t0 = t[0], t1 = t[1], t2 = t[2];

    const int n_beg  = c * chunk;              // chunk % 4 == 0 -> aligned
    const int n_end  = min(N, n_beg + chunk);
    const int nquads = (n_end - n_beg + 3) >> 2;

    for (int q = threadIdx.x; q < nquads; q += BLOCK_THREADS) {
        const int n0 = n_beg + (q << 2);
        // 4 points = 48B = 3x float4 (n0 multiple of 4 -> 16B aligned).
        const float4* vp = (const float4*)(vertices + ((size_t)b * N + n0) * 3);
        const float4 f0 = vp[0], f1 = vp[1], f2 = vp[2];
        const float pxv[4][3] = {{f0.x, f0.y, f0.z}, {f0.w, f1.x, f1.y},
                                 {f1.z, f1.w, f2.x}, {f2.y, f2.z, f2.w}};
#pragma unroll
        for (int kk = 0; kk < 4; ++kk) {
            const int n = n0 + kk;
            if (n >= n_end) break;
            const float v0 = pxv[kk][0], v1 = pxv[kk][1], v2 = pxv[kk][2];

            // FROZEN FP ORDER (single exact projection per point).
            const float y = dot3_fwd_nofma(v0, v1, v2, R10, R11, R12, t1);
            const float z = dot3_fwd_nofma(v0, v1, v2, R20, R21, R22, t2);
            const float Z = z + 1e-8f;          // separate round
            const float qy = y / Z;             // correctly-rounded div
            float w = fy * qy;                  // separate mul
            w = w + cy;                         // separate add
            const float tv = truncf(w);
            if (!(tv >= 0.0f && tv < (float)RH)) continue;  // NaN -> skip

            const float x = dot3_fwd_nofma(v0, v1, v2, R00, R01, R02, t0);
            const float qx = x / Z;
            float u = fx * qx;
            u = u + cx;
            const float tu = truncf(u);
            if (!(tu >= 0.0f && tu < (float)RW)) continue;

            const unsigned int p  = (unsigned int)((int)tv * RW + (int)tu);
            const unsigned int sh = (p & 1u) << 4;        // halfword shift
            const unsigned int val = (unsigned int)(n - n_beg + 1);  // <=chunk
            unsigned int* wp = &sbuf[p >> 1];
            unsigned int cur = *wp;
            while (((cur >> sh) & 0xFFFFu) < val) {       // u16 CAS-max
                const unsigned int nw =
                    (cur & ~(0xFFFFu << sh)) | (val << sh);
                const unsigned int prev = atomicCAS(wp, cur, nw);
                if (prev == cur) break;
                cur = prev;
            }
        }
    }
    __syncthreads();

    // Plain uint4 streaming stores into this block's private ws slice.
    uint4* dst = (uint4*)(ws + (size_t)blk * LDSW);
    const uint4* src = (const uint4*)sbuf;
    for (int j = threadIdx.x; j < LDSW / 4; j += BLOCK_THREADS)
        dst[j] = src[j];
}

// Resolve: 4 pixels/thread. Scan copies in ASCENDING chunk order; a nonzero
// later copy strictly wins -> conditional overwrite (no compare-max needed).
// Decode n = c*chunk + local - 1; recompute depth (frozen FP).
__global__ void resolve16_kernel(const unsigned short* __restrict__ ws16,
                                 const float* __restrict__ vertices,
                                 const float* __restrict__ rotation,
                                 const float* __restrict__ translation,
                                 float* __restrict__ out, int N, int chunk,
                                 int P) {
#pragma clang fp contract(off)
    const int g = blockIdx.x * blockDim.x + threadIdx.x;   // 4-pixel group
    if (g >= P / 4) return;
    const int i0  = g << 2;
    const int b   = i0 / HW;
    const int pix = i0 - b * HW;                 // multiple of 4

    const unsigned short* base = ws16 + ((size_t)b * NCHUNK) * HW + pix;
    unsigned int m0 = 0u, m1 = 0u, m2 = 0u, m3 = 0u;
#pragma unroll
    for (int c = 0; c < NCHUNK; ++c) {
        const uint2 v2 = *(const uint2*)(base + (size_t)c * HW);
        const unsigned int ck = (unsigned int)(c + 1) << 16;
        unsigned int v;
        v = v2.x & 0xFFFFu; if (v) m0 = ck | v;
        v = v2.x >> 16;     if (v) m1 = ck | v;
        v = v2.y & 0xFFFFu; if (v) m2 = ck | v;
        v = v2.y >> 16;     if (v) m3 = ck | v;
    }

    const unsigned int mm[4] = {m0, m1, m2, m3};
    float4 o;
    float* op = (float*)&o;
#pragma unroll
    for (int j = 0; j < 4; ++j) {
        float depth = 0.0f;
        const unsigned int m = mm[j];
        if (m != 0u) {
            const int c = (int)(m >> 16) - 1;
            const int n = c * chunk + (int)(m & 0xFFFFu) - 1;
            const float* v = vertices + ((size_t)b * (size_t)N + (size_t)n) * 3;
            const float* R = rotation + b * 9;
            depth = dot3_fwd_nofma(v[0], v[1], v[2], R[6], R[7], R[8],
                                   translation[b * 3 + 2]);
        }
        op[j] = depth;
    }
    *(float4*)(out + i0) = o;
}

// ---------------- fallback path (r11: u32 LDS stripes + atomic flush) ------
#define NSTRIPE 2
#define STRIPE_ROWS (RH / NSTRIPE)
#define STRIPE_PX (STRIPE_ROWS * RW)

__global__ __launch_bounds__(BLOCK_THREADS) void
proj_fb_kernel(const float* __restrict__ vertices,
               const float* __restrict__ rotation,
               const float* __restrict__ translation,
               const float* __restrict__ Kmat,
               unsigned int* __restrict__ win, int N) {
#pragma clang fp contract(off)
    extern __shared__ unsigned int sbuf[];
    const int blk = (int)blockIdx.x;
    const int s   = blk & (NSTRIPE - 1);
    const int c   = (blk >> 1) & 7;
    const int b   = blk >> 4;
    for (int j = threadIdx.x; j < STRIPE_PX; j += BLOCK_THREADS) sbuf[j] = 0u;
    __syncthreads();
    const float* R = rotation + b * 9;
    const float* t = translation + b * 3;
    const float* k = Kmat + b * 9;
    const float fx = k[0], cx = k[2], fy = k[4], cy = k[5];
    const float R00 = R[0], R01 = R[1], R02 = R[2];
    const float R10 = R[3], R11 = R[4], R12 = R[5];
    const float R20 = R[6], R21 = R[7], R22 = R[8];
    const float t0 = t[0], t1 = t[1], t2 = t[2];
    const int chunk  = (N + 7) / 8;
    const int n_beg  = c * chunk;
    const int n_end  = min(N, n_beg + chunk);
    const int nquads = (n_end - n_beg + 3) >> 2;
    const float v_lo = (float)(s * STRIPE_ROWS);
    const float v_hi = (float)((s + 1) * STRIPE_ROWS);
    for (int q = threadIdx.x; q < nquads; q += BLOCK_THREADS) {
        const int n0 = n_beg + (q << 2);
        const float4* vp = (const float4*)(vertices + ((size_t)b * N + n0) * 3);
        const float4 f0 = vp[0], f1 = vp[1], f2 = vp[2];
        const float pxv[4][3] = {{f0.x, f0.y, f0.z}, {f0.w, f1.x, f1.y},
                                 {f1.z, f1.w, f2.x}, {f2.y, f2.z, f2.w}};
#pragma unroll
        for (int kk = 0; kk < 4; ++kk) {
            const int n = n0 + kk;
            if (n >= n_end) break;
            const float v0 = pxv[kk][0], v1 = pxv[kk][1], v2 = pxv[kk][2];
            const float y = dot3_fwd_nofma(v0, v1, v2, R10, R11, R12, t1);
            const float z = dot3_fwd_nofma(v0, v1, v2, R20, R21, R22, t2);
            const float Z = z + 1e-8f;
            const float qy = y / Z;
            float w = fy * qy;
            w = w + cy;
            const float tv = truncf(w);
            if (!(tv >= v_lo && tv < v_hi)) continue;
            const float x = dot3_fwd_nofma(v0, v1, v2, R00, R01, R02, t0);
            const float qx = x / Z;
            float u = fx * qx;
            u = u + cx;
            const float tu = truncf(u);
            if (!(tu >= 0.0f && tu < (float)RW)) continue;
            const int slot = ((int)tv - s * STRIPE_ROWS) * RW + (int)tu;
            atomicMax(&sbuf[slot], (unsigned int)(b * N + n) + 1u);
        }
    }
    __syncthreads();
    unsigned int* g = win + b * HW + s * STRIPE_PX;
    for (int j = threadIdx.x; j < STRIPE_PX; j += BLOCK_THREADS) {
        const unsigned int val = sbuf[j];
        if (val) atomicMax(&g[j], val);
    }
}

__global__ void resolve_fb_kernel(unsigned int* __restrict__ buf,
                                  const float* __restrict__ vertices,
                                  const float* __restrict__ rotation,
                                  const float* __restrict__ translation,
                                  int N, int P) {
#pragma clang fp contract(off)
    const int i = blockIdx.x * blockDim.x + threadIdx.x;
    if (i >= P) return;
    const unsigned int o1 = buf[i];
    float depth = 0.0f;
    if (o1 != 0u) {
        const unsigned int o = o1 - 1u;
        const int b = (int)(o / (unsigned int)N);
        const int n = (int)(o % (unsigned int)N);
        const float* v = vertices + ((size_t)b * (size_t)N + (size_t)n) * 3;
        const float* R = rotation + b * 9;
        depth = dot3_fwd_nofma(v[0], v[1], v[2], R[6], R[7], R[8],
                               translation[b * 3 + 2]);
    }
    buf[i] = __float_as_uint(depth);
}

extern "C" void kernel_launch(void* const* d_in, const int* in_sizes, int n_in,
                              void* d_out, int out_size, void* d_ws, size_t ws_size,
                              hipStream_t stream) {
    const float* vertices    = (const float*)d_in[0];
    const float* rotation    = (const float*)d_in[1];
    const float* translation = (const float*)d_in[2];
    const float* Kmat        = (const float*)d_in[3];

    const int B = in_sizes[1] / 9;              // rotation is B*3*3
    const int N = in_sizes[0] / (3 * B);        // vertices is B*N*3
    const int P = B * HW;                       // == out_size
    const int nblocks = B * NCHUNK;             // 256 = 1 block/CU
    const int chunk = (((N + NCHUNK - 1) / NCHUNK) + 3) & ~3;  // 31252, %4==0

    const size_t ws_needed = (size_t)nblocks * LDSW * sizeof(unsigned int);

    if (ws_size >= ws_needed && chunk < 65536 && (P & 3) == 0) {
        unsigned int* ws = (unsigned int*)d_ws;
        proj16_kernel<<<nblocks, BLOCK_THREADS,
                        LDSW * sizeof(unsigned int), stream>>>(
            vertices, rotation, translation, Kmat, ws, N, chunk);
        const int rthreads = P / 4;
        const int rblocks = (rthreads + 255) / 256;
        resolve16_kernel<<<rblocks, 256, 0, stream>>>(
            (const unsigned short*)d_ws, vertices, rotation, translation,
            (float*)d_out, N, chunk, P);
    } else {
        unsigned int* win = (unsigned int*)d_out;
        hipMemsetAsync(win, 0, (size_t)P * sizeof(unsigned int), stream);
        proj_fb_kernel<<<B * 16, BLOCK_THREADS,
                         STRIPE_PX * sizeof(unsigned int), stream>>>(
            vertices, rotation, translation, Kmat, win, N);
        const int rblocks = (P + 255) / 256;
        resolve_fb_kernel<<<rblocks, 256, 0, stream>>>(win, vertices, rotation,
                                                       translation, N, P);
    }
}